// Round 12
// baseline (241.184 us; speedup 1.0000x reference)
//
#include <hip/hip_runtime.h>
#include <hip/hip_bf16.h>
#include <math.h>

#define BH_ 32
#define N_ 4096
#define D_ 64
#define SAMP_ 256
#define SC2_ 0.1803368801111244f   // SCALE * log2(e)
#define HPAD 68

typedef __attribute__((ext_vector_type(4))) float f32x4;
typedef __attribute__((ext_vector_type(8))) short bf16x8;
typedef __attribute__((ext_vector_type(4))) short bf16x4;

static __device__ __forceinline__ unsigned pack2(float a, float b) {
    union { __hip_bfloat162 h; unsigned u; } c;
    c.h = __float22bfloat162_rn(make_float2(a, b));
    return c.u;
}

static __device__ __forceinline__ bf16x8 cvt8v(f32x4 a, f32x4 b) {
    union { unsigned u[4]; bf16x8 v; } r;
    r.u[0] = pack2(a[0], a[1]); r.u[1] = pack2(a[2], a[3]);
    r.u[2] = pack2(b[0], b[1]); r.u[3] = pack2(b[2], b[3]);
    return r.v;
}

static __device__ __forceinline__ bf16x8 cvt8(const float* p) {
    return cvt8v(*(const f32x4*)p, *(const f32x4*)(p + 4));
}

// ---------------- 1. LSH hash (working) -------------------------------------
__global__ __launch_bounds__(128) void hash_kernel(
    const float* __restrict__ q, const float* __restrict__ k,
    const float* __restrict__ pd,
    unsigned char* __restrict__ qbuck, unsigned char* __restrict__ kbuck)
{
    extern __shared__ char smraw[];
    float*  Xs  = (float*)smraw;
    double* Pdl = (double*)(smraw + 128 * HPAD * 4);

    int tid = threadIdx.x;
    const float* src = blockIdx.y ? k : q;
    unsigned char* dst = blockIdx.y ? kbuck : qbuck;
    size_t tok0 = (size_t)blockIdx.x * 128;

    {
        int d = tid >> 1, r0 = (tid & 1) * 4;
#pragma unroll
        for (int j = 0; j < 4; ++j)
            Pdl[d * 8 + r0 + j] = (double)pd[d * 8 + r0 + j];
    }
    {
        const float4* src4 = (const float4*)(src + tok0 * D_);
        for (int i = tid; i < 128 * 16; i += 128) {
            int r = i >> 4, c = i & 15;
            *(float4*)&Xs[r * HPAD + c * 4] = src4[i];
        }
    }
    __syncthreads();

    float xr[64];
#pragma unroll
    for (int c = 0; c < 16; ++c)
        *(f32x4*)&xr[c * 4] = *(const f32x4*)&Xs[tid * HPAD + c * 4];

    double acc[8];
#pragma unroll
    for (int r = 0; r < 8; ++r) acc[r] = 0.0;
#pragma unroll
    for (int d = 0; d < 64; ++d) {
        double x = (double)xr[d];
        const double* pr = Pdl + d * 8;
#pragma unroll
        for (int r = 0; r < 8; ++r) acc[r] += x * pr[r];
    }
    int bin = 0;
#pragma unroll
    for (int r = 0; r < 8; ++r)
        if (acc[r] > 0.0) bin |= (1 << r);
    dst[tok0 + tid] = (unsigned char)(bin ^ (bin >> 1));
}

// ---------------- 2. stable counting sort (working) -------------------------
__global__ __launch_bounds__(256) void sort_kernel(
    const unsigned char* __restrict__ qbuck,
    const unsigned char* __restrict__ kbuck,
    int* __restrict__ q_idx, int* __restrict__ k_idx)
{
    __shared__ unsigned short hist[64][256];
    __shared__ unsigned int   binstart[256];
    __shared__ alignas(16) unsigned char bl[N_];

    int bh = blockIdx.x, tensor = blockIdx.y;
    const unsigned char* buck = (tensor ? kbuck : qbuck) + bh * N_;
    int* idx_out = (tensor ? k_idx : q_idx) + bh * N_;
    int t = threadIdx.x;

    ((uint4*)bl)[t] = ((const uint4*)buck)[t];
    {
        uint4* h4 = (uint4*)&hist[0][0];
        for (int i = t; i < 2048; i += 256) h4[i] = make_uint4(0, 0, 0, 0);
    }
    __syncthreads();

    if (t < 64) {
        for (int u = 0; u < 64; ++u) hist[t][bl[t * 64 + u]]++;
    }
    __syncthreads();

    {
        unsigned run = 0;
        for (int tt = 0; tt < 64; ++tt) {
            unsigned c = hist[tt][t];
            hist[tt][t] = (unsigned short)run;
            run += c;
        }
        binstart[t] = run;
    }
    __syncthreads();

    if (t < 64) {
        unsigned b0 = binstart[t*4], b1 = binstart[t*4+1],
                 b2 = binstart[t*4+2], b3 = binstart[t*4+3];
        unsigned s = b0 + b1 + b2 + b3, p = s;
#pragma unroll
        for (int d = 1; d < 64; d <<= 1) {
            unsigned y = __shfl_up(p, d);
            if (t >= d) p += y;
        }
        unsigned e = p - s;
        binstart[t*4]   = e;
        binstart[t*4+1] = e + b0;
        binstart[t*4+2] = e + b0 + b1;
        binstart[t*4+3] = e + b0 + b1 + b2;
    }
    __syncthreads();

    if (t < 64) {
        for (int u = 0; u < 64; ++u) {
            int tok = t * 64 + u;
            int b = bl[tok];
            int pos = (int)(binstart[b] + hist[t][b]);
            hist[t][b]++;
            idx_out[pos] = tok;
        }
    }
}

// ---------------- 3. fused attention: true 32 waves/CU, no spills -----------
// 1024 wgs x 512 thr (8 waves x 16 queries). 8 phases of 64 keys (4 block +
// 4 sampled). LDS 16 KB/wg -> 4 wgs/CU x 8 waves = 32 waves/CU, 256 CUs
// exactly covered. Staging: each thread 8 K floats + 8 V floats SEQUENTIALLY
// (peak 16 transient VGPR; audited total ~50 < 64-cap of (512,8)).
// K stage write r=tid&63 -> quarter-wave-linear (2-way, free). K LDS
// [kt(4)][ks(2)][lg(4)][ll(16)][8]; V LDS = R9-verified tr-subtile image.
// exp folded: e = exp2(fma(s, SCALE*log2e, bias2)), bias2 = log2(16) = 4.
__global__ __launch_bounds__(512, 8) void fused_attn(
    const float* __restrict__ query, const float* __restrict__ key,
    const float* __restrict__ value, const int* __restrict__ q_idx,
    const int* __restrict__ k_idx, const int* __restrict__ sampled,
    float* __restrict__ out)
{
    __shared__ __align__(16) short Ksm[4096];   // 8 KB (64 keys x 64 d)
    __shared__ __align__(16) short Vsm[4096];   // 8 KB
    int wgid = blockIdx.x;
    int wg = (wgid & 7) * 128 + (wgid >> 3);    // bijective XCD swizzle
    int bh = wg >> 5, sub = wg & 31;            // 128-query slice
    int tid = threadIdx.x, w = tid >> 6, l = tid & 63, lg = l >> 4, ll = l & 15;
    size_t base = (size_t)bh * N_;

    const int* kidxA = k_idx + base + (sub >> 1) * 256;
    const int* kidxB = sampled + bh * SAMP_;

    // staging decomposition (64 keys x 64 d; 8 floats K + 8 floats V each)
    int rK = l, d0K = w * 8;                     // K: row = lane, d = wave*8
    int koff = (rK >> 4) * 1024 + (w >> 2) * 512 + (w & 3) * 128 + (rK & 15) * 8;
    int vrow = (w >> 2) * 32 + (w & 3) * 8 + (l >> 5) * 4 + ((l >> 1) & 3);
    int vd   = ((l >> 3) & 3) * 16 + (l & 1) * 8;

    // Q fragment (wave owns 16 queries)
    const int* qidx = q_idx + base + sub * 128 + w * 16;
    int qr = qidx[ll];
    const float* qp = query + (base + (size_t)qr) * D_ + lg * 8;
    bf16x8 qf[2] = { cvt8(qp), cvt8(qp + 32) };

    f32x4 o[4];
#pragma unroll
    for (int dt = 0; dt < 4; ++dt) { f32x4 z = {0.f,0.f,0.f,0.f}; o[dt] = z; }
    float lsum = 0.f;
    unsigned vtr = (unsigned)(unsigned long long)(void*)&Vsm[0] + lg * 512 + ll * 8;

#define STAGE_(KI, VI) do { \
        const float* kp_ = key + (base + (size_t)(KI)) * D_ + d0K; \
        f32x4 ka_ = *(const f32x4*)kp_, kb_ = *(const f32x4*)(kp_ + 4); \
        *(bf16x8*)&Ksm[koff] = cvt8v(ka_, kb_); \
        const float* vp_ = value + (base + (size_t)(VI)) * D_ + vd; \
        f32x4 va_ = *(const f32x4*)vp_, vb_ = *(const f32x4*)(vp_ + 4); \
        *(bf16x8*)&Vsm[tid * 8] = cvt8v(va_, vb_); } while (0)

#define COMPUTE_(BIAS2) do { \
        _Pragma("unroll") \
        for (int hgi = 0; hgi < 2; ++hgi) { \
            unsigned pbu[4]; \
            __builtin_amdgcn_s_setprio(1); \
            _Pragma("unroll") \
            for (int t = 0; t < 2; ++t) { \
                int kt = hgi * 2 + t; \
                f32x4 s = {0.f,0.f,0.f,0.f}; \
                _Pragma("unroll") \
                for (int ks = 0; ks < 2; ++ks) { \
                    bf16x8 a = *(const bf16x8*)&Ksm[kt * 1024 + ks * 512 + lg * 128 + ll * 8]; \
                    s = __builtin_amdgcn_mfma_f32_16x16x32_bf16(a, qf[ks], s, 0, 0, 0); \
                } \
                __builtin_amdgcn_s_setprio(0); \
                f32x4 e; \
                _Pragma("unroll") \
                for (int r = 0; r < 4; ++r) e[r] = exp2f(fmaf(s[r], SC2_, (BIAS2))); \
                lsum += (e[0] + e[1]) + (e[2] + e[3]); \
                pbu[t*2]   = pack2(e[0], e[1]); \
                pbu[t*2+1] = pack2(e[2], e[3]); \
                __builtin_amdgcn_s_setprio(1); \
            } \
            bf16x8 pb; \
            { union { unsigned u[4]; bf16x8 v; } cc_; \
              cc_.u[0]=pbu[0]; cc_.u[1]=pbu[1]; cc_.u[2]=pbu[2]; cc_.u[3]=pbu[3]; pb=cc_.v; } \
            bf16x4 tr[4][2]; \
            _Pragma("unroll") \
            for (int dt = 0; dt < 4; ++dt) { \
                asm volatile("ds_read_b64_tr_b16 %0, %1 offset:%2" \
                             : "=v"(tr[dt][0]) : "v"(vtr), "i"(hgi * 4096 + dt * 128)); \
                asm volatile("ds_read_b64_tr_b16 %0, %1 offset:%2" \
                             : "=v"(tr[dt][1]) : "v"(vtr), "i"(hgi * 4096 + dt * 128 + 2048)); \
            } \
            asm volatile("s_waitcnt lgkmcnt(0)" ::: "memory"); \
            __builtin_amdgcn_sched_barrier(0); \
            _Pragma("unroll") \
            for (int dt = 0; dt < 4; ++dt) { \
                union { bf16x4 h[2]; bf16x8 v; } va2; \
                va2.h[0] = tr[dt][0]; va2.h[1] = tr[dt][1]; \
                o[dt] = __builtin_amdgcn_mfma_f32_16x16x32_bf16(va2.v, pb, o[dt], 0, 0, 0); \
            } \
            __builtin_amdgcn_s_setprio(0); \
        } } while (0)

    // ---- 8 phases: 4 block-key (bias2 0) + 4 sampled (bias2 4)
    int kI = kidxA[rK], vI = kidxA[vrow];
#pragma unroll
    for (int p = 0; p < 8; ++p) {
        STAGE_(kI, vI);
        __syncthreads();
        if (p < 7) {   // prefetch next phase's gather indices (2 regs)
            const int* nx = (p + 1 < 4) ? (kidxA + (p + 1) * 64)
                                        : (kidxB + (p - 3) * 64);
            kI = nx[rK]; vI = nx[vrow];
        }
        if (p < 4) COMPUTE_(0.f); else COMPUTE_(4.f);
        __syncthreads();
    }
#undef STAGE_
#undef COMPUTE_

    // ---- row-sum over lg groups; epilogue out = o / l
    lsum += __shfl_xor(lsum, 16);
    lsum += __shfl_xor(lsum, 32);

    float dn = 1.f / lsum;
    float* orow = out + (base + (size_t)qr) * D_ + lg * 4;
#pragma unroll
    for (int dt = 0; dt < 4; ++dt) {
        f32x4 v = o[dt] * dn;
        *(f32x4*)&orow[dt * 16] = v;
    }
}

// ---------------------------------------------------------------------------
extern "C" void kernel_launch(void* const* d_in, const int* in_sizes, int n_in,
                              void* d_out, int out_size, void* d_ws, size_t ws_size,
                              hipStream_t stream)
{
    const float* query = (const float*)d_in[0];
    const float* key   = (const float*)d_in[1];
    const float* value = (const float*)d_in[2];
    const float* pd    = (const float*)d_in[3];
    const int*   samp  = (const int*)d_in[4];
    float* out = (float*)d_out;

    char* ws = (char*)d_ws;
    unsigned char* qbuck = (unsigned char*)ws;                 // 128 KB
    unsigned char* kbuck = qbuck + (size_t)BH_ * N_;           // 128 KB
    int* q_idx = (int*)(ws + 262144);                          // 512 KB
    int* k_idx = (int*)(ws + 262144 + 524288);                 // 512 KB

    size_t hash_lds = 128 * HPAD * 4 + 512 * 8;
    hipLaunchKernelGGL(hash_kernel, dim3(BH_ * N_ / 128, 2), dim3(128),
                       hash_lds, stream, query, key, pd, qbuck, kbuck);
    hipLaunchKernelGGL(sort_kernel, dim3(BH_, 2), dim3(256), 0, stream,
                       qbuck, kbuck, q_idx, k_idx);
    hipLaunchKernelGGL(fused_attn, dim3(1024), dim3(512), 0, stream,
                       query, key, value, q_idx, k_idx, samp, out);
}

// Round 13
// 116.926 us; speedup vs baseline: 2.0627x; 2.0627x over previous
//
#include <hip/hip_runtime.h>
#include <hip/hip_bf16.h>
#include <math.h>

#define BH_ 32
#define N_ 4096
#define D_ 64
#define SAMP_ 256
#define SC2_ 0.1803368801111244f   // SCALE * log2(e)
#define HPAD 68

typedef __attribute__((ext_vector_type(4))) float f32x4;
typedef __attribute__((ext_vector_type(8))) short bf16x8;
typedef __attribute__((ext_vector_type(4))) short bf16x4;

static __device__ __forceinline__ unsigned pack2(float a, float b) {
    union { __hip_bfloat162 h; unsigned u; } c;
    c.h = __float22bfloat162_rn(make_float2(a, b));
    return c.u;
}

static __device__ __forceinline__ bf16x8 cvt8v(f32x4 a, f32x4 b) {
    union { unsigned u[4]; bf16x8 v; } r;
    r.u[0] = pack2(a[0], a[1]); r.u[1] = pack2(a[2], a[3]);
    r.u[2] = pack2(b[0], b[1]); r.u[3] = pack2(b[2], b[3]);
    return r.v;
}

static __device__ __forceinline__ bf16x8 cvt8(const float* p) {
    return cvt8v(*(const f32x4*)p, *(const f32x4*)(p + 4));
}

// ---------------- 1. LSH hash (working) -------------------------------------
__global__ __launch_bounds__(128) void hash_kernel(
    const float* __restrict__ q, const float* __restrict__ k,
    const float* __restrict__ pd,
    unsigned char* __restrict__ qbuck, unsigned char* __restrict__ kbuck)
{
    extern __shared__ char smraw[];
    float*  Xs  = (float*)smraw;
    double* Pdl = (double*)(smraw + 128 * HPAD * 4);

    int tid = threadIdx.x;
    const float* src = blockIdx.y ? k : q;
    unsigned char* dst = blockIdx.y ? kbuck : qbuck;
    size_t tok0 = (size_t)blockIdx.x * 128;

    {
        int d = tid >> 1, r0 = (tid & 1) * 4;
#pragma unroll
        for (int j = 0; j < 4; ++j)
            Pdl[d * 8 + r0 + j] = (double)pd[d * 8 + r0 + j];
    }
    {
        const float4* src4 = (const float4*)(src + tok0 * D_);
        for (int i = tid; i < 128 * 16; i += 128) {
            int r = i >> 4, c = i & 15;
            *(float4*)&Xs[r * HPAD + c * 4] = src4[i];
        }
    }
    __syncthreads();

    float xr[64];
#pragma unroll
    for (int c = 0; c < 16; ++c)
        *(f32x4*)&xr[c * 4] = *(const f32x4*)&Xs[tid * HPAD + c * 4];

    double acc[8];
#pragma unroll
    for (int r = 0; r < 8; ++r) acc[r] = 0.0;
#pragma unroll
    for (int d = 0; d < 64; ++d) {
        double x = (double)xr[d];
        const double* pr = Pdl + d * 8;
#pragma unroll
        for (int r = 0; r < 8; ++r) acc[r] += x * pr[r];
    }
    int bin = 0;
#pragma unroll
    for (int r = 0; r < 8; ++r)
        if (acc[r] > 0.0) bin |= (1 << r);
    dst[tok0 + tid] = (unsigned char)(bin ^ (bin >> 1));
}

// ---------------- 2. stable counting sort (working) -------------------------
__global__ __launch_bounds__(256) void sort_kernel(
    const unsigned char* __restrict__ qbuck,
    const unsigned char* __restrict__ kbuck,
    int* __restrict__ q_idx, int* __restrict__ k_idx)
{
    __shared__ unsigned short hist[64][256];
    __shared__ unsigned int   binstart[256];
    __shared__ alignas(16) unsigned char bl[N_];

    int bh = blockIdx.x, tensor = blockIdx.y;
    const unsigned char* buck = (tensor ? kbuck : qbuck) + bh * N_;
    int* idx_out = (tensor ? k_idx : q_idx) + bh * N_;
    int t = threadIdx.x;

    ((uint4*)bl)[t] = ((const uint4*)buck)[t];
    {
        uint4* h4 = (uint4*)&hist[0][0];
        for (int i = t; i < 2048; i += 256) h4[i] = make_uint4(0, 0, 0, 0);
    }
    __syncthreads();

    if (t < 64) {
        for (int u = 0; u < 64; ++u) hist[t][bl[t * 64 + u]]++;
    }
    __syncthreads();

    {
        unsigned run = 0;
        for (int tt = 0; tt < 64; ++tt) {
            unsigned c = hist[tt][t];
            hist[tt][t] = (unsigned short)run;
            run += c;
        }
        binstart[t] = run;
    }
    __syncthreads();

    if (t < 64) {
        unsigned b0 = binstart[t*4], b1 = binstart[t*4+1],
                 b2 = binstart[t*4+2], b3 = binstart[t*4+3];
        unsigned s = b0 + b1 + b2 + b3, p = s;
#pragma unroll
        for (int d = 1; d < 64; d <<= 1) {
            unsigned y = __shfl_up(p, d);
            if (t >= d) p += y;
        }
        unsigned e = p - s;
        binstart[t*4]   = e;
        binstart[t*4+1] = e + b0;
        binstart[t*4+2] = e + b0 + b1;
        binstart[t*4+3] = e + b0 + b1 + b2;
    }
    __syncthreads();

    if (t < 64) {
        for (int u = 0; u < 64; ++u) {
            int tok = t * 64 + u;
            int b = bl[tok];
            int pos = (int)(binstart[b] + hist[t][b]);
            hist[t][b]++;
            idx_out[pos] = tok;
        }
    }
}

// ---------------- 3. fused attention ----------------------------------------
// 1024 wgs x 512 thr (8 waves x 16 queries), 8 phases x 64 keys (4 block +
// 4 sampled). LDS 16 KB/wg. __launch_bounds__(512,4): allocator free up to
// 128 VGPR; kernel lands ~55-60 -> HARDWARE runs 8 waves/SIMD organically
// (occupancy follows actual VGPR, not the bound), 4 wgs/CU, no spills.
// COMPUTE pipeline: per hgi issue tr-reads FIRST, then QK MFMA + exp cover
// the DS latency (in-order lgkm return: compiler's K-read waits subsume tr),
// so the rule-#18 drain before PV is ~free.
// exp folded: e = exp2(fma(s, SCALE*log2e, bias2)), bias2 = log2(16) = 4.
__global__ __launch_bounds__(512, 4) void fused_attn(
    const float* __restrict__ query, const float* __restrict__ key,
    const float* __restrict__ value, const int* __restrict__ q_idx,
    const int* __restrict__ k_idx, const int* __restrict__ sampled,
    float* __restrict__ out)
{
    __shared__ __align__(16) short Ksm[4096];   // 8 KB (64 keys x 64 d)
    __shared__ __align__(16) short Vsm[4096];   // 8 KB
    int wgid = blockIdx.x;
    int wg = (wgid & 7) * 128 + (wgid >> 3);    // bijective XCD swizzle
    int bh = wg >> 5, sub = wg & 31;            // 128-query slice
    int tid = threadIdx.x, w = tid >> 6, l = tid & 63, lg = l >> 4, ll = l & 15;
    size_t base = (size_t)bh * N_;

    const int* kidxA = k_idx + base + (sub >> 1) * 256;
    const int* kidxB = sampled + bh * SAMP_;

    // staging decomposition (64 keys x 64 d; 8 K floats + 8 V floats each)
    int rK = l, d0K = w * 8;
    int koff = (rK >> 4) * 1024 + (w >> 2) * 512 + (w & 3) * 128 + (rK & 15) * 8;
    int vrow = (w >> 2) * 32 + (w & 3) * 8 + (l >> 5) * 4 + ((l >> 1) & 3);
    int vd   = ((l >> 3) & 3) * 16 + (l & 1) * 8;

    // Q fragment (wave owns 16 queries)
    const int* qidx = q_idx + base + sub * 128 + w * 16;
    int qr = qidx[ll];
    const float* qp = query + (base + (size_t)qr) * D_ + lg * 8;
    bf16x8 qf[2] = { cvt8(qp), cvt8(qp + 32) };

    f32x4 o[4];
#pragma unroll
    for (int dt = 0; dt < 4; ++dt) { f32x4 z = {0.f,0.f,0.f,0.f}; o[dt] = z; }
    float lsum = 0.f;
    unsigned vtr = (unsigned)(unsigned long long)(void*)&Vsm[0] + lg * 512 + ll * 8;

#define STAGE_(KI, VI) do { \
        const float* kp_ = key + (base + (size_t)(KI)) * D_ + d0K; \
        f32x4 ka_ = *(const f32x4*)kp_, kb_ = *(const f32x4*)(kp_ + 4); \
        *(bf16x8*)&Ksm[koff] = cvt8v(ka_, kb_); \
        const float* vp_ = value + (base + (size_t)(VI)) * D_ + vd; \
        f32x4 va_ = *(const f32x4*)vp_, vb_ = *(const f32x4*)(vp_ + 4); \
        *(bf16x8*)&Vsm[tid * 8] = cvt8v(va_, vb_); } while (0)

#define COMPUTE_(BIAS2) do { \
        _Pragma("unroll") \
        for (int hgi = 0; hgi < 2; ++hgi) { \
            /* 1. issue tr-reads first -> DS latency hides under QK+exp */ \
            bf16x4 tr[4][2]; \
            _Pragma("unroll") \
            for (int dt = 0; dt < 4; ++dt) { \
                asm volatile("ds_read_b64_tr_b16 %0, %1 offset:%2" \
                             : "=v"(tr[dt][0]) : "v"(vtr), "i"(hgi * 4096 + dt * 128)); \
                asm volatile("ds_read_b64_tr_b16 %0, %1 offset:%2" \
                             : "=v"(tr[dt][1]) : "v"(vtr), "i"(hgi * 4096 + dt * 128 + 2048)); \
            } \
            /* 2. QK^T + softmax (covers tr latency) */ \
            unsigned pbu[4]; \
            __builtin_amdgcn_s_setprio(1); \
            _Pragma("unroll") \
            for (int t = 0; t < 2; ++t) { \
                int kt = hgi * 2 + t; \
                f32x4 s = {0.f,0.f,0.f,0.f}; \
                _Pragma("unroll") \
                for (int ks = 0; ks < 2; ++ks) { \
                    bf16x8 a = *(const bf16x8*)&Ksm[kt * 1024 + ks * 512 + lg * 128 + ll * 8]; \
                    s = __builtin_amdgcn_mfma_f32_16x16x32_bf16(a, qf[ks], s, 0, 0, 0); \
                } \
                f32x4 e; \
                _Pragma("unroll") \
                for (int r = 0; r < 4; ++r) e[r] = exp2f(fmaf(s[r], SC2_, (BIAS2))); \
                lsum += (e[0] + e[1]) + (e[2] + e[3]); \
                pbu[t*2]   = pack2(e[0], e[1]); \
                pbu[t*2+1] = pack2(e[2], e[3]); \
            } \
            bf16x8 pb; \
            { union { unsigned u[4]; bf16x8 v; } cc_; \
              cc_.u[0]=pbu[0]; cc_.u[1]=pbu[1]; cc_.u[2]=pbu[2]; cc_.u[3]=pbu[3]; pb=cc_.v; } \
            /* 3. drain (cheap now) + fence (rule #18), then PV */ \
            asm volatile("s_waitcnt lgkmcnt(0)" ::: "memory"); \
            __builtin_amdgcn_sched_barrier(0); \
            _Pragma("unroll") \
            for (int dt = 0; dt < 4; ++dt) { \
                union { bf16x4 h[2]; bf16x8 v; } va2; \
                va2.h[0] = tr[dt][0]; va2.h[1] = tr[dt][1]; \
                o[dt] = __builtin_amdgcn_mfma_f32_16x16x32_bf16(va2.v, pb, o[dt], 0, 0, 0); \
            } \
            __builtin_amdgcn_s_setprio(0); \
        } } while (0)

    // ---- 8 phases: 4 block-key (bias2 0) + 4 sampled (bias2 4)
    int kI = kidxA[rK], vI = kidxA[vrow];
#pragma unroll
    for (int p = 0; p < 8; ++p) {
        STAGE_(kI, vI);
        __syncthreads();
        if (p < 7) {   // prefetch next phase's gather indices (2 regs)
            const int* nx = (p + 1 < 4) ? (kidxA + (p + 1) * 64)
                                        : (kidxB + (p - 3) * 64);
            kI = nx[rK]; vI = nx[vrow];
        }
        if (p < 4) COMPUTE_(0.f); else COMPUTE_(4.f);
        __syncthreads();
    }
#undef STAGE_
#undef COMPUTE_

    // ---- row-sum over lg groups; epilogue out = o / l
    lsum += __shfl_xor(lsum, 16);
    lsum += __shfl_xor(lsum, 32);

    float dn = 1.f / lsum;
    float* orow = out + (base + (size_t)qr) * D_ + lg * 4;
#pragma unroll
    for (int dt = 0; dt < 4; ++dt) {
        f32x4 v = o[dt] * dn;
        *(f32x4*)&orow[dt * 16] = v;
    }
}

// ---------------------------------------------------------------------------
extern "C" void kernel_launch(void* const* d_in, const int* in_sizes, int n_in,
                              void* d_out, int out_size, void* d_ws, size_t ws_size,
                              hipStream_t stream)
{
    const float* query = (const float*)d_in[0];
    const float* key   = (const float*)d_in[1];
    const float* value = (const float*)d_in[2];
    const float* pd    = (const float*)d_in[3];
    const int*   samp  = (const int*)d_in[4];
    float* out = (float*)d_out;

    char* ws = (char*)d_ws;
    unsigned char* qbuck = (unsigned char*)ws;                 // 128 KB
    unsigned char* kbuck = qbuck + (size_t)BH_ * N_;           // 128 KB
    int* q_idx = (int*)(ws + 262144);                          // 512 KB
    int* k_idx = (int*)(ws + 262144 + 524288);                 // 512 KB

    size_t hash_lds = 128 * HPAD * 4 + 512 * 8;
    hipLaunchKernelGGL(hash_kernel, dim3(BH_ * N_ / 128, 2), dim3(128),
                       hash_lds, stream, query, key, pd, qbuck, kbuck);
    hipLaunchKernelGGL(sort_kernel, dim3(BH_, 2), dim3(256), 0, stream,
                       qbuck, kbuck, q_idx, k_idx);
    hipLaunchKernelGGL(fused_attn, dim3(1024), dim3(512), 0, stream,
                       query, key, value, q_idx, k_idx, samp, out);
}

// Round 14
// 83.047 us; speedup vs baseline: 2.9042x; 1.4080x over previous
//
#include <hip/hip_runtime.h>
#include <hip/hip_bf16.h>
#include <math.h>

#define BH_ 32
#define N_ 4096
#define D_ 64
#define SAMP_ 256
#define SC2_ 0.1803368801111244f   // SCALE * log2(e)
#define HPAD 68

typedef __attribute__((ext_vector_type(4))) float f32x4;
typedef __attribute__((ext_vector_type(8))) short bf16x8;
typedef __attribute__((ext_vector_type(4))) short bf16x4;

static __device__ __forceinline__ unsigned pack2(float a, float b) {
    union { __hip_bfloat162 h; unsigned u; } c;
    c.h = __float22bfloat162_rn(make_float2(a, b));
    return c.u;
}

static __device__ __forceinline__ bf16x8 cvt8v(f32x4 a, f32x4 b) {
    union { unsigned u[4]; bf16x8 v; } r;
    r.u[0] = pack2(a[0], a[1]); r.u[1] = pack2(a[2], a[3]);
    r.u[2] = pack2(b[0], b[1]); r.u[3] = pack2(b[2], b[3]);
    return r.v;
}

static __device__ __forceinline__ bf16x8 cvt8(const float* p) {
    return cvt8v(*(const f32x4*)p, *(const f32x4*)(p + 4));
}

// ---------------- 1. LSH hash (working) -------------------------------------
__global__ __launch_bounds__(128) void hash_kernel(
    const float* __restrict__ q, const float* __restrict__ k,
    const float* __restrict__ pd,
    unsigned char* __restrict__ qbuck, unsigned char* __restrict__ kbuck)
{
    extern __shared__ char smraw[];
    float*  Xs  = (float*)smraw;
    double* Pdl = (double*)(smraw + 128 * HPAD * 4);

    int tid = threadIdx.x;
    const float* src = blockIdx.y ? k : q;
    unsigned char* dst = blockIdx.y ? kbuck : qbuck;
    size_t tok0 = (size_t)blockIdx.x * 128;

    {
        int d = tid >> 1, r0 = (tid & 1) * 4;
#pragma unroll
        for (int j = 0; j < 4; ++j)
            Pdl[d * 8 + r0 + j] = (double)pd[d * 8 + r0 + j];
    }
    {
        const float4* src4 = (const float4*)(src + tok0 * D_);
        for (int i = tid; i < 128 * 16; i += 128) {
            int r = i >> 4, c = i & 15;
            *(float4*)&Xs[r * HPAD + c * 4] = src4[i];
        }
    }
    __syncthreads();

    float xr[64];
#pragma unroll
    for (int c = 0; c < 16; ++c)
        *(f32x4*)&xr[c * 4] = *(const f32x4*)&Xs[tid * HPAD + c * 4];

    double acc[8];
#pragma unroll
    for (int r = 0; r < 8; ++r) acc[r] = 0.0;
#pragma unroll
    for (int d = 0; d < 64; ++d) {
        double x = (double)xr[d];
        const double* pr = Pdl + d * 8;
#pragma unroll
        for (int r = 0; r < 8; ++r) acc[r] += x * pr[r];
    }
    int bin = 0;
#pragma unroll
    for (int r = 0; r < 8; ++r)
        if (acc[r] > 0.0) bin |= (1 << r);
    dst[tok0 + tid] = (unsigned char)(bin ^ (bin >> 1));
}

// ---------------- 2. stable counting sort (working) -------------------------
__global__ __launch_bounds__(256) void sort_kernel(
    const unsigned char* __restrict__ qbuck,
    const unsigned char* __restrict__ kbuck,
    int* __restrict__ q_idx, int* __restrict__ k_idx)
{
    __shared__ unsigned short hist[64][256];
    __shared__ unsigned int   binstart[256];
    __shared__ alignas(16) unsigned char bl[N_];

    int bh = blockIdx.x, tensor = blockIdx.y;
    const unsigned char* buck = (tensor ? kbuck : qbuck) + bh * N_;
    int* idx_out = (tensor ? k_idx : q_idx) + bh * N_;
    int t = threadIdx.x;

    ((uint4*)bl)[t] = ((const uint4*)buck)[t];
    {
        uint4* h4 = (uint4*)&hist[0][0];
        for (int i = t; i < 2048; i += 256) h4[i] = make_uint4(0, 0, 0, 0);
    }
    __syncthreads();

    if (t < 64) {
        for (int u = 0; u < 64; ++u) hist[t][bl[t * 64 + u]]++;
    }
    __syncthreads();

    {
        unsigned run = 0;
        for (int tt = 0; tt < 64; ++tt) {
            unsigned c = hist[tt][t];
            hist[tt][t] = (unsigned short)run;
            run += c;
        }
        binstart[t] = run;
    }
    __syncthreads();

    if (t < 64) {
        unsigned b0 = binstart[t*4], b1 = binstart[t*4+1],
                 b2 = binstart[t*4+2], b3 = binstart[t*4+3];
        unsigned s = b0 + b1 + b2 + b3, p = s;
#pragma unroll
        for (int d = 1; d < 64; d <<= 1) {
            unsigned y = __shfl_up(p, d);
            if (t >= d) p += y;
        }
        unsigned e = p - s;
        binstart[t*4]   = e;
        binstart[t*4+1] = e + b0;
        binstart[t*4+2] = e + b0 + b1;
        binstart[t*4+3] = e + b0 + b1 + b2;
    }
    __syncthreads();

    if (t < 64) {
        for (int u = 0; u < 64; ++u) {
            int tok = t * 64 + u;
            int b = bl[tok];
            int pos = (int)(binstart[b] + hist[t][b]);
            hist[t][b]++;
            idx_out[pos] = tok;
        }
    }
}

// ---------------- 3. fused attention: 2 mega-phases, de-phased waves --------
// R10 structure (known-good: 60 VGPR, no spill): 512 wgs x 512 thr, per phase
// ALL 256 keys+values staged into 64KB LDS once, then 8 chunks of 32 keys
// computed barrier-free. NEW vs R10:
//  (1) per-wave rotated chunk order hgi = (i+w)&7 -> the 8 waves touch
//      different chunks at any instant; stalls decorrelate (anti-convoy).
//  (2) tr-reads issued BEFORE QK MFMA per chunk -> DS latency hidden.
//  (3) exp2 folding: e = exp2(fma(s, SCALE*log2e, bias2)), bias2=log2(16)=4.
static __device__ __forceinline__ void stage_kv(
    const float* __restrict__ key, const float* __restrict__ value,
    size_t base, int krI, int v0, int v1, int v2, int v3,
    int hK, int kwofs, int vd, int tid, short* Ksm, short* Vsm)
{
    {
        const float* kp = key + (base + (size_t)krI) * D_ + hK * 32;
        f32x4 k0 = *(const f32x4*)kp,        k1 = *(const f32x4*)(kp + 4);
        f32x4 k2 = *(const f32x4*)(kp + 8),  k3 = *(const f32x4*)(kp + 12);
        f32x4 k4 = *(const f32x4*)(kp + 16), k5 = *(const f32x4*)(kp + 20);
        f32x4 k6 = *(const f32x4*)(kp + 24), k7 = *(const f32x4*)(kp + 28);
        *(bf16x8*)&Ksm[kwofs]       = cvt8v(k0, k1);
        *(bf16x8*)&Ksm[kwofs + 128] = cvt8v(k2, k3);
        *(bf16x8*)&Ksm[kwofs + 256] = cvt8v(k4, k5);
        *(bf16x8*)&Ksm[kwofs + 384] = cvt8v(k6, k7);
    }
    {
        const float* vp0 = value + (base + (size_t)v0) * D_ + vd;
        const float* vp1 = value + (base + (size_t)v1) * D_ + vd;
        const float* vp2 = value + (base + (size_t)v2) * D_ + vd;
        const float* vp3 = value + (base + (size_t)v3) * D_ + vd;
        f32x4 a0 = *(const f32x4*)vp0, b0 = *(const f32x4*)(vp0 + 4);
        f32x4 a1 = *(const f32x4*)vp1, b1 = *(const f32x4*)(vp1 + 4);
        f32x4 a2 = *(const f32x4*)vp2, b2 = *(const f32x4*)(vp2 + 4);
        f32x4 a3 = *(const f32x4*)vp3, b3 = *(const f32x4*)(vp3 + 4);
        *(bf16x8*)&Vsm[tid * 8]         = cvt8v(a0, b0);
        *(bf16x8*)&Vsm[4096 + tid * 8]  = cvt8v(a1, b1);
        *(bf16x8*)&Vsm[8192 + tid * 8]  = cvt8v(a2, b2);
        *(bf16x8*)&Vsm[12288 + tid * 8] = cvt8v(a3, b3);
    }
}

static __device__ __forceinline__ void compute_256(
    const short* __restrict__ Ksm, unsigned vtrbase, float bias2,
    const bf16x8 (&qf)[2][2], int w, int lg, int ll,
    f32x4 (&o)[4][2], float (&lsum)[2])
{
#pragma unroll
    for (int i = 0; i < 8; ++i) {
        int hgi = (i + w) & 7;                    // per-wave chunk rotation
        unsigned vtr = vtrbase + hgi * 4096;      // byte addr of V chunk
        const short* Kc = Ksm + hgi * 2048;       // 2 kt-tiles per chunk

        // 1. issue tr-reads first -> DS latency hides under QK + exp
        bf16x4 tr[4][2];
#pragma unroll
        for (int dt = 0; dt < 4; ++dt) {
            asm volatile("ds_read_b64_tr_b16 %0, %1 offset:%2"
                         : "=v"(tr[dt][0]) : "v"(vtr), "i"(dt * 128));
            asm volatile("ds_read_b64_tr_b16 %0, %1 offset:%2"
                         : "=v"(tr[dt][1]) : "v"(vtr), "i"(dt * 128 + 2048));
        }

        // 2. QK^T + softmax
        unsigned pbu[2][4];
        __builtin_amdgcn_s_setprio(1);
#pragma unroll
        for (int t = 0; t < 2; ++t) {
            f32x4 s0 = {0.f,0.f,0.f,0.f}, s1 = {0.f,0.f,0.f,0.f};
#pragma unroll
            for (int ks = 0; ks < 2; ++ks) {
                bf16x8 a = *(const bf16x8*)&Kc[t * 1024 + ks * 512 + lg * 128 + ll * 8];
                s0 = __builtin_amdgcn_mfma_f32_16x16x32_bf16(a, qf[0][ks], s0, 0, 0, 0);
                s1 = __builtin_amdgcn_mfma_f32_16x16x32_bf16(a, qf[1][ks], s1, 0, 0, 0);
            }
            __builtin_amdgcn_s_setprio(0);
            f32x4 e0, e1;
#pragma unroll
            for (int r = 0; r < 4; ++r) {
                e0[r] = exp2f(fmaf(s0[r], SC2_, bias2));
                e1[r] = exp2f(fmaf(s1[r], SC2_, bias2));
            }
            lsum[0] += (e0[0] + e0[1]) + (e0[2] + e0[3]);
            lsum[1] += (e1[0] + e1[1]) + (e1[2] + e1[3]);
            pbu[0][t*2]   = pack2(e0[0], e0[1]);
            pbu[0][t*2+1] = pack2(e0[2], e0[3]);
            pbu[1][t*2]   = pack2(e1[0], e1[1]);
            pbu[1][t*2+1] = pack2(e1[2], e1[3]);
            __builtin_amdgcn_s_setprio(1);
        }
        bf16x8 pb0, pb1;
        { union { unsigned u[4]; bf16x8 v; } cc;
          cc.u[0]=pbu[0][0]; cc.u[1]=pbu[0][1]; cc.u[2]=pbu[0][2]; cc.u[3]=pbu[0][3]; pb0=cc.v; }
        { union { unsigned u[4]; bf16x8 v; } cc;
          cc.u[0]=pbu[1][0]; cc.u[1]=pbu[1][1]; cc.u[2]=pbu[1][2]; cc.u[3]=pbu[1][3]; pb1=cc.v; }

        // 3. drain (mostly complete by now) + fence (rule #18), then PV
        asm volatile("s_waitcnt lgkmcnt(0)" ::: "memory");
        __builtin_amdgcn_sched_barrier(0);
#pragma unroll
        for (int dt = 0; dt < 4; ++dt) {
            union { bf16x4 h[2]; bf16x8 v; } va;
            va.h[0] = tr[dt][0]; va.h[1] = tr[dt][1];
            o[dt][0] = __builtin_amdgcn_mfma_f32_16x16x32_bf16(va.v, pb0, o[dt][0], 0, 0, 0);
            o[dt][1] = __builtin_amdgcn_mfma_f32_16x16x32_bf16(va.v, pb1, o[dt][1], 0, 0, 0);
        }
        __builtin_amdgcn_s_setprio(0);
    }
}

__global__ __launch_bounds__(512, 4) void fused_attn(
    const float* __restrict__ query, const float* __restrict__ key,
    const float* __restrict__ value, const int* __restrict__ q_idx,
    const int* __restrict__ k_idx, const int* __restrict__ sampled,
    float* __restrict__ out)
{
    __shared__ __align__(16) short Ksm[16384];   // 32 KB
    __shared__ __align__(16) short Vsm[16384];   // 32 KB
    int wgid = blockIdx.x;
    int wg = (wgid & 7) * 64 + (wgid >> 3);      // bijective XCD swizzle
    int bh = wg >> 4, blk = wg & 15;
    int tid = threadIdx.x, w = tid >> 6, l = tid & 63, lg = l >> 4, ll = l & 15;
    size_t base = (size_t)bh * N_;

    const int* kidxA = k_idx + base + blk * 256;
    const int* kidxB = sampled + bh * SAMP_;

    // staging decomposition
    int rK = tid & 255, hK = tid >> 8;
    int kwofs = (rK >> 4) * 1024 + hK * 512 + (rK & 15) * 8;
    int l6 = tid & 63, i6 = tid >> 6;
    int vrow = (i6 >> 2) * 32 + (l6 >> 5) * 4 + ((l6 >> 1) & 3) + (i6 & 3) * 8;
    int vd   = (((l6 >> 3) & 3) * 2 + (l6 & 1)) * 8;

    // phase A indices
    int krA = kidxA[rK];
    int vA0 = kidxA[vrow],       vA1 = kidxA[64 + vrow];
    int vA2 = kidxA[128 + vrow], vA3 = kidxA[192 + vrow];

    // Q fragments (wave owns 32 queries)
    const int* qidx = q_idx + base + blk * 256 + w * 32;
    int qr[2]; bf16x8 qf[2][2];
#pragma unroll
    for (int mt = 0; mt < 2; ++mt) {
        qr[mt] = qidx[mt * 16 + ll];
        const float* qp = query + (base + (size_t)qr[mt]) * D_;
#pragma unroll
        for (int ks = 0; ks < 2; ++ks)
            qf[mt][ks] = cvt8(qp + ks * 32 + lg * 8);
    }

    f32x4 o[4][2]; float lsum[2];
#pragma unroll
    for (int mt = 0; mt < 2; ++mt) {
        lsum[mt] = 0.f;
#pragma unroll
        for (int dt = 0; dt < 4; ++dt) { f32x4 z = {0.f,0.f,0.f,0.f}; o[dt][mt] = z; }
    }
    unsigned vtrbase = (unsigned)(unsigned long long)(void*)&Vsm[0] + lg * 512 + ll * 8;

    // ---- phase A: stage, sync, compute (B indices prefetched under compute)
    stage_kv(key, value, base, krA, vA0, vA1, vA2, vA3, hK, kwofs, vd, tid, Ksm, Vsm);
    __syncthreads();

    int krB = kidxB[rK];
    int vB0 = kidxB[vrow],       vB1 = kidxB[64 + vrow];
    int vB2 = kidxB[128 + vrow], vB3 = kidxB[192 + vrow];

    compute_256(Ksm, vtrbase, 0.f, qf, w, lg, ll, o, lsum);
    __syncthreads();

    // ---- phase B
    stage_kv(key, value, base, krB, vB0, vB1, vB2, vB3, hK, kwofs, vd, tid, Ksm, Vsm);
    __syncthreads();
    compute_256(Ksm, vtrbase, 4.f, qf, w, lg, ll, o, lsum);

    // ---- row-sum over lg groups; epilogue out = o / l
#pragma unroll
    for (int mt = 0; mt < 2; ++mt) {
        float v = lsum[mt];
        v += __shfl_xor(v, 16);
        v += __shfl_xor(v, 32);
        lsum[mt] = v;
    }
#pragma unroll
    for (int mt = 0; mt < 2; ++mt) {
        float dn = 1.f / lsum[mt];
        float* orow = out + (base + (size_t)qr[mt]) * D_ + lg * 4;
#pragma unroll
        for (int dt = 0; dt < 4; ++dt) {
            f32x4 v = o[dt][mt] * dn;
            *(f32x4*)&orow[dt * 16] = v;
        }
    }
}

// ---------------------------------------------------------------------------
extern "C" void kernel_launch(void* const* d_in, const int* in_sizes, int n_in,
                              void* d_out, int out_size, void* d_ws, size_t ws_size,
                              hipStream_t stream)
{
    const float* query = (const float*)d_in[0];
    const float* key   = (const float*)d_in[1];
    const float* value = (const float*)d_in[2];
    const float* pd    = (const float*)d_in[3];
    const int*   samp  = (const int*)d_in[4];
    float* out = (float*)d_out;

    char* ws = (char*)d_ws;
    unsigned char* qbuck = (unsigned char*)ws;                 // 128 KB
    unsigned char* kbuck = qbuck + (size_t)BH_ * N_;           // 128 KB
    int* q_idx = (int*)(ws + 262144);                          // 512 KB
    int* k_idx = (int*)(ws + 262144 + 524288);                 // 512 KB

    size_t hash_lds = 128 * HPAD * 4 + 512 * 8;
    hipLaunchKernelGGL(hash_kernel, dim3(BH_ * N_ / 128, 2), dim3(128),
                       hash_lds, stream, query, key, pd, qbuck, kbuck);
    hipLaunchKernelGGL(sort_kernel, dim3(BH_, 2), dim3(256), 0, stream,
                       qbuck, kbuck, q_idx, k_idx);
    hipLaunchKernelGGL(fused_attn, dim3(512), dim3(512), 0, stream,
                       query, key, value, q_idx, k_idx, samp, out);
}

// Round 15
// 82.196 us; speedup vs baseline: 2.9343x; 1.0104x over previous
//
#include <hip/hip_runtime.h>
#include <hip/hip_bf16.h>
#include <math.h>

#define BH_ 32
#define N_ 4096
#define D_ 64
#define SAMP_ 256
#define SC2_ 0.1803368801111244f   // SCALE * log2(e)
#define HPAD 68

typedef __attribute__((ext_vector_type(4))) float f32x4;
typedef __attribute__((ext_vector_type(8))) short bf16x8;
typedef __attribute__((ext_vector_type(4))) short bf16x4;

static __device__ __forceinline__ unsigned pack2(float a, float b) {
    union { __hip_bfloat162 h; unsigned u; } c;
    c.h = __float22bfloat162_rn(make_float2(a, b));
    return c.u;
}

static __device__ __forceinline__ bf16x8 cvt8v(f32x4 a, f32x4 b) {
    union { unsigned u[4]; bf16x8 v; } r;
    r.u[0] = pack2(a[0], a[1]); r.u[1] = pack2(a[2], a[3]);
    r.u[2] = pack2(b[0], b[1]); r.u[3] = pack2(b[2], b[3]);
    return r.v;
}

static __device__ __forceinline__ bf16x8 cvt8(const float* p) {
    return cvt8v(*(const f32x4*)p, *(const f32x4*)(p + 4));
}

// ---------------- 1. LSH hash (working) -------------------------------------
__global__ __launch_bounds__(128) void hash_kernel(
    const float* __restrict__ q, const float* __restrict__ k,
    const float* __restrict__ pd,
    unsigned char* __restrict__ qbuck, unsigned char* __restrict__ kbuck)
{
    extern __shared__ char smraw[];
    float*  Xs  = (float*)smraw;
    double* Pdl = (double*)(smraw + 128 * HPAD * 4);

    int tid = threadIdx.x;
    const float* src = blockIdx.y ? k : q;
    unsigned char* dst = blockIdx.y ? kbuck : qbuck;
    size_t tok0 = (size_t)blockIdx.x * 128;

    {
        int d = tid >> 1, r0 = (tid & 1) * 4;
#pragma unroll
        for (int j = 0; j < 4; ++j)
            Pdl[d * 8 + r0 + j] = (double)pd[d * 8 + r0 + j];
    }
    {
        const float4* src4 = (const float4*)(src + tok0 * D_);
        for (int i = tid; i < 128 * 16; i += 128) {
            int r = i >> 4, c = i & 15;
            *(float4*)&Xs[r * HPAD + c * 4] = src4[i];
        }
    }
    __syncthreads();

    float xr[64];
#pragma unroll
    for (int c = 0; c < 16; ++c)
        *(f32x4*)&xr[c * 4] = *(const f32x4*)&Xs[tid * HPAD + c * 4];

    double acc[8];
#pragma unroll
    for (int r = 0; r < 8; ++r) acc[r] = 0.0;
#pragma unroll
    for (int d = 0; d < 64; ++d) {
        double x = (double)xr[d];
        const double* pr = Pdl + d * 8;
#pragma unroll
        for (int r = 0; r < 8; ++r) acc[r] += x * pr[r];
    }
    int bin = 0;
#pragma unroll
    for (int r = 0; r < 8; ++r)
        if (acc[r] > 0.0) bin |= (1 << r);
    dst[tok0 + tid] = (unsigned char)(bin ^ (bin >> 1));
}

// ---------------- 2. stable counting sort (working) -------------------------
__global__ __launch_bounds__(256) void sort_kernel(
    const unsigned char* __restrict__ qbuck,
    const unsigned char* __restrict__ kbuck,
    int* __restrict__ q_idx, int* __restrict__ k_idx)
{
    __shared__ unsigned short hist[64][256];
    __shared__ unsigned int   binstart[256];
    __shared__ alignas(16) unsigned char bl[N_];

    int bh = blockIdx.x, tensor = blockIdx.y;
    const unsigned char* buck = (tensor ? kbuck : qbuck) + bh * N_;
    int* idx_out = (tensor ? k_idx : q_idx) + bh * N_;
    int t = threadIdx.x;

    ((uint4*)bl)[t] = ((const uint4*)buck)[t];
    {
        uint4* h4 = (uint4*)&hist[0][0];
        for (int i = t; i < 2048; i += 256) h4[i] = make_uint4(0, 0, 0, 0);
    }
    __syncthreads();

    if (t < 64) {
        for (int u = 0; u < 64; ++u) hist[t][bl[t * 64 + u]]++;
    }
    __syncthreads();

    {
        unsigned run = 0;
        for (int tt = 0; tt < 64; ++tt) {
            unsigned c = hist[tt][t];
            hist[tt][t] = (unsigned short)run;
            run += c;
        }
        binstart[t] = run;
    }
    __syncthreads();

    if (t < 64) {
        unsigned b0 = binstart[t*4], b1 = binstart[t*4+1],
                 b2 = binstart[t*4+2], b3 = binstart[t*4+3];
        unsigned s = b0 + b1 + b2 + b3, p = s;
#pragma unroll
        for (int d = 1; d < 64; d <<= 1) {
            unsigned y = __shfl_up(p, d);
            if (t >= d) p += y;
        }
        unsigned e = p - s;
        binstart[t*4]   = e;
        binstart[t*4+1] = e + b0;
        binstart[t*4+2] = e + b0 + b1;
        binstart[t*4+3] = e + b0 + b1 + b2;
    }
    __syncthreads();

    if (t < 64) {
        for (int u = 0; u < 64; ++u) {
            int tok = t * 64 + u;
            int b = bl[tok];
            int pos = (int)(binstart[b] + hist[t][b]);
            hist[t][b]++;
            idx_out[pos] = tok;
        }
    }
}

// ---------------- 3. fused attention: 2 mega-phases, soft-fenced ------------
// R10 structure (known-good: 60 VGPR, no spill, 59us): 512 wgs x 512 thr,
// per phase ALL 256 keys+values staged into 64KB LDS once, then 8 chunks of
// 32 keys computed barrier-free. CHANGE vs R10: the rule-#18 fence
// (lgkmcnt(0) + sched_barrier(0), 2x per chunk) is replaced by a
// REGISTER-DEPENDENCY wait: the s_waitcnt asm takes all 8 tr values as "+v"
// in-outs -> it must follow the tr-reads and precede the PV MFMAs, but the
// compiler is free to software-pipeline chunk i+1's K-reads / QK MFMAs / exp
// across it (no sched_barrier, no memory clobber). exp2 folding: e =
// exp2(fma(s, SCALE*log2e, bias2)), bias2 = log2(16) = 4 exact.
static __device__ __forceinline__ void stage_kv(
    const float* __restrict__ key, const float* __restrict__ value,
    size_t base, int krI, int v0, int v1, int v2, int v3,
    int hK, int kwofs, int vd, int tid, short* Ksm, short* Vsm)
{
    {
        const float* kp = key + (base + (size_t)krI) * D_ + hK * 32;
        f32x4 k0 = *(const f32x4*)kp,        k1 = *(const f32x4*)(kp + 4);
        f32x4 k2 = *(const f32x4*)(kp + 8),  k3 = *(const f32x4*)(kp + 12);
        f32x4 k4 = *(const f32x4*)(kp + 16), k5 = *(const f32x4*)(kp + 20);
        f32x4 k6 = *(const f32x4*)(kp + 24), k7 = *(const f32x4*)(kp + 28);
        *(bf16x8*)&Ksm[kwofs]       = cvt8v(k0, k1);
        *(bf16x8*)&Ksm[kwofs + 128] = cvt8v(k2, k3);
        *(bf16x8*)&Ksm[kwofs + 256] = cvt8v(k4, k5);
        *(bf16x8*)&Ksm[kwofs + 384] = cvt8v(k6, k7);
    }
    {
        const float* vp0 = value + (base + (size_t)v0) * D_ + vd;
        const float* vp1 = value + (base + (size_t)v1) * D_ + vd;
        const float* vp2 = value + (base + (size_t)v2) * D_ + vd;
        const float* vp3 = value + (base + (size_t)v3) * D_ + vd;
        f32x4 a0 = *(const f32x4*)vp0, b0 = *(const f32x4*)(vp0 + 4);
        f32x4 a1 = *(const f32x4*)vp1, b1 = *(const f32x4*)(vp1 + 4);
        f32x4 a2 = *(const f32x4*)vp2, b2 = *(const f32x4*)(vp2 + 4);
        f32x4 a3 = *(const f32x4*)vp3, b3 = *(const f32x4*)(vp3 + 4);
        *(bf16x8*)&Vsm[tid * 8]         = cvt8v(a0, b0);
        *(bf16x8*)&Vsm[4096 + tid * 8]  = cvt8v(a1, b1);
        *(bf16x8*)&Vsm[8192 + tid * 8]  = cvt8v(a2, b2);
        *(bf16x8*)&Vsm[12288 + tid * 8] = cvt8v(a3, b3);
    }
}

static __device__ __forceinline__ void compute_256(
    const short* __restrict__ Ksm, unsigned vtr0, float bias2,
    const bf16x8 (&qf)[2][2], int lg, int ll,
    f32x4 (&o)[4][2], float (&lsum)[2])
{
#pragma unroll
    for (int hgi = 0; hgi < 8; ++hgi) {
        // ---- QK^T + softmax (R10 order: K-reads first, trs after)
        unsigned pbu[2][4];
        __builtin_amdgcn_s_setprio(1);
#pragma unroll
        for (int t = 0; t < 2; ++t) {
            int kt = hgi * 2 + t;
            f32x4 s0 = {0.f,0.f,0.f,0.f}, s1 = {0.f,0.f,0.f,0.f};
#pragma unroll
            for (int ks = 0; ks < 2; ++ks) {
                bf16x8 a = *(const bf16x8*)&Ksm[kt * 1024 + ks * 512 + lg * 128 + ll * 8];
                s0 = __builtin_amdgcn_mfma_f32_16x16x32_bf16(a, qf[0][ks], s0, 0, 0, 0);
                s1 = __builtin_amdgcn_mfma_f32_16x16x32_bf16(a, qf[1][ks], s1, 0, 0, 0);
            }
            __builtin_amdgcn_s_setprio(0);
            f32x4 e0, e1;
#pragma unroll
            for (int r = 0; r < 4; ++r) {
                e0[r] = exp2f(fmaf(s0[r], SC2_, bias2));
                e1[r] = exp2f(fmaf(s1[r], SC2_, bias2));
            }
            lsum[0] += (e0[0] + e0[1]) + (e0[2] + e0[3]);
            lsum[1] += (e1[0] + e1[1]) + (e1[2] + e1[3]);
            pbu[0][t*2]   = pack2(e0[0], e0[1]);
            pbu[0][t*2+1] = pack2(e0[2], e0[3]);
            pbu[1][t*2]   = pack2(e1[0], e1[1]);
            pbu[1][t*2+1] = pack2(e1[2], e1[3]);
            __builtin_amdgcn_s_setprio(1);
        }
        bf16x8 pb0, pb1;
        { union { unsigned u[4]; bf16x8 v; } cc;
          cc.u[0]=pbu[0][0]; cc.u[1]=pbu[0][1]; cc.u[2]=pbu[0][2]; cc.u[3]=pbu[0][3]; pb0=cc.v; }
        { union { unsigned u[4]; bf16x8 v; } cc;
          cc.u[0]=pbu[1][0]; cc.u[1]=pbu[1][1]; cc.u[2]=pbu[1][2]; cc.u[3]=pbu[1][3]; pb1=cc.v; }

        // ---- V^T fragments via tr-reads
        bf16x4 tr[4][2];
#pragma unroll
        for (int dt = 0; dt < 4; ++dt) {
            asm volatile("ds_read_b64_tr_b16 %0, %1 offset:%2"
                         : "=v"(tr[dt][0]) : "v"(vtr0), "i"(hgi * 4096 + dt * 128));
            asm volatile("ds_read_b64_tr_b16 %0, %1 offset:%2"
                         : "=v"(tr[dt][1]) : "v"(vtr0), "i"(hgi * 4096 + dt * 128 + 2048));
        }
        // register-dependency wait: follows tr-reads (reads them), precedes
        // PV (defines them). NO sched_barrier / memory clobber -> compiler
        // may pipeline next chunk's loads+MFMAs across this point.
        asm volatile("s_waitcnt lgkmcnt(0)"
                     : "+v"(tr[0][0]), "+v"(tr[0][1]), "+v"(tr[1][0]), "+v"(tr[1][1]),
                       "+v"(tr[2][0]), "+v"(tr[2][1]), "+v"(tr[3][0]), "+v"(tr[3][1]));
#pragma unroll
        for (int dt = 0; dt < 4; ++dt) {
            union { bf16x4 h[2]; bf16x8 v; } va;
            va.h[0] = tr[dt][0]; va.h[1] = tr[dt][1];
            o[dt][0] = __builtin_amdgcn_mfma_f32_16x16x32_bf16(va.v, pb0, o[dt][0], 0, 0, 0);
            o[dt][1] = __builtin_amdgcn_mfma_f32_16x16x32_bf16(va.v, pb1, o[dt][1], 0, 0, 0);
        }
        __builtin_amdgcn_s_setprio(0);
    }
}

__global__ __launch_bounds__(512, 4) void fused_attn(
    const float* __restrict__ query, const float* __restrict__ key,
    const float* __restrict__ value, const int* __restrict__ q_idx,
    const int* __restrict__ k_idx, const int* __restrict__ sampled,
    float* __restrict__ out)
{
    __shared__ __align__(16) short Ksm[16384];   // 32 KB
    __shared__ __align__(16) short Vsm[16384];   // 32 KB
    int wgid = blockIdx.x;
    int wg = (wgid & 7) * 64 + (wgid >> 3);      // bijective XCD swizzle
    int bh = wg >> 4, blk = wg & 15;
    int tid = threadIdx.x, w = tid >> 6, l = tid & 63, lg = l >> 4, ll = l & 15;
    size_t base = (size_t)bh * N_;

    const int* kidxA = k_idx + base + blk * 256;
    const int* kidxB = sampled + bh * SAMP_;

    // staging decomposition
    int rK = tid & 255, hK = tid >> 8;
    int kwofs = (rK >> 4) * 1024 + hK * 512 + (rK & 15) * 8;
    int l6 = tid & 63, i6 = tid >> 6;
    int vrow = (i6 >> 2) * 32 + (l6 >> 5) * 4 + ((l6 >> 1) & 3) + (i6 & 3) * 8;
    int vd   = (((l6 >> 3) & 3) * 2 + (l6 & 1)) * 8;

    // phase A indices
    int krA = kidxA[rK];
    int vA0 = kidxA[vrow],       vA1 = kidxA[64 + vrow];
    int vA2 = kidxA[128 + vrow], vA3 = kidxA[192 + vrow];

    // Q fragments (wave owns 32 queries)
    const int* qidx = q_idx + base + blk * 256 + w * 32;
    int qr[2]; bf16x8 qf[2][2];
#pragma unroll
    for (int mt = 0; mt < 2; ++mt) {
        qr[mt] = qidx[mt * 16 + ll];
        const float* qp = query + (base + (size_t)qr[mt]) * D_;
#pragma unroll
        for (int ks = 0; ks < 2; ++ks)
            qf[mt][ks] = cvt8(qp + ks * 32 + lg * 8);
    }

    f32x4 o[4][2]; float lsum[2];
#pragma unroll
    for (int mt = 0; mt < 2; ++mt) {
        lsum[mt] = 0.f;
#pragma unroll
        for (int dt = 0; dt < 4; ++dt) { f32x4 z = {0.f,0.f,0.f,0.f}; o[dt][mt] = z; }
    }
    unsigned vtr0 = (unsigned)(unsigned long long)(void*)&Vsm[0] + lg * 512 + ll * 8;

    // ---- phase A: stage, sync, compute (B indices prefetched under compute)
    stage_kv(key, value, base, krA, vA0, vA1, vA2, vA3, hK, kwofs, vd, tid, Ksm, Vsm);
    __syncthreads();

    int krB = kidxB[rK];
    int vB0 = kidxB[vrow],       vB1 = kidxB[64 + vrow];
    int vB2 = kidxB[128 + vrow], vB3 = kidxB[192 + vrow];

    compute_256(Ksm, vtr0, 0.f, qf, lg, ll, o, lsum);
    __syncthreads();

    // ---- phase B
    stage_kv(key, value, base, krB, vB0, vB1, vB2, vB3, hK, kwofs, vd, tid, Ksm, Vsm);
    __syncthreads();
    compute_256(Ksm, vtr0, 4.f, qf, lg, ll, o, lsum);

    // ---- row-sum over lg groups; epilogue out = o / l
#pragma unroll
    for (int mt = 0; mt < 2; ++mt) {
        float v = lsum[mt];
        v += __shfl_xor(v, 16);
        v += __shfl_xor(v, 32);
        lsum[mt] = v;
    }
#pragma unroll
    for (int mt = 0; mt < 2; ++mt) {
        float dn = 1.f / lsum[mt];
        float* orow = out + (base + (size_t)qr[mt]) * D_ + lg * 4;
#pragma unroll
        for (int dt = 0; dt < 4; ++dt) {
            f32x4 v = o[dt][mt] * dn;
            *(f32x4*)&orow[dt * 16] = v;
        }
    }
}

// ---------------------------------------------------------------------------
extern "C" void kernel_launch(void* const* d_in, const int* in_sizes, int n_in,
                              void* d_out, int out_size, void* d_ws, size_t ws_size,
                              hipStream_t stream)
{
    const float* query = (const float*)d_in[0];
    const float* key   = (const float*)d_in[1];
    const float* value = (const float*)d_in[2];
    const float* pd    = (const float*)d_in[3];
    const int*   samp  = (const int*)d_in[4];
    float* out = (float*)d_out;

    char* ws = (char*)d_ws;
    unsigned char* qbuck = (unsigned char*)ws;                 // 128 KB
    unsigned char* kbuck = qbuck + (size_t)BH_ * N_;           // 128 KB
    int* q_idx = (int*)(ws + 262144);                          // 512 KB
    int* k_idx = (int*)(ws + 262144 + 524288);                 // 512 KB

    size_t hash_lds = 128 * HPAD * 4 + 512 * 8;
    hipLaunchKernelGGL(hash_kernel, dim3(BH_ * N_ / 128, 2), dim3(128),
                       hash_lds, stream, query, key, pd, qbuck, kbuck);
    hipLaunchKernelGGL(sort_kernel, dim3(BH_, 2), dim3(256), 0, stream,
                       qbuck, kbuck, q_idx, k_idx);
    hipLaunchKernelGGL(fused_attn, dim3(512), dim3(512), 0, stream,
                       query, key, value, q_idx, k_idx, samp, out);
}